// Round 1
// baseline (643.997 us; speedup 1.0000x reference)
//
#include <hip/hip_runtime.h>

// JointSlotFusion on MI355X.
// ws layout: kbuf bf16[128][2048][64] | vbuf same | wconv bf16[2][64][256] | wkv bf16[2][64][64]
// total 67,190,784 bytes.

typedef __bf16 bf16;
typedef __bf16 bf16x8 __attribute__((ext_vector_type(8)));
typedef float  f32x4  __attribute__((ext_vector_type(4)));

#define MFMA16(a, b, c) __builtin_amdgcn_mfma_f32_16x16x32_bf16((a), (b), (c), 0, 0, 0)

// ---------------- K0: weight fp32 -> bf16 ----------------
__global__ __launch_bounds__(256) void k0_convert(
    const float* __restrict__ c1w, const float* __restrict__ c2w,
    const float* __restrict__ wk,  const float* __restrict__ wvv,
    bf16* __restrict__ wconv, bf16* __restrict__ wkv)
{
  const int i = blockIdx.x * 256 + threadIdx.x;   // 64 blocks -> 16384 threads
  if (i < 16384) {
    wconv[i]         = (bf16)c1w[i];
    wconv[16384 + i] = (bf16)c2w[i];
  }
  if (i < 4096) {
    wkv[i]        = (bf16)wk[i];
    wkv[4096 + i] = (bf16)wvv[i];
  }
}

// ---------------- K1: conv1x1 + LN + LN + k/v GEMM ----------------
// grid 4096 = 128 b * 2 img * 16 pixel-tiles of 64; block 256 (4 waves)
__global__ __launch_bounds__(256) void k1_conv_kv(
    const float* __restrict__ x1, const float* __restrict__ x2,
    const float* __restrict__ c1b, const float* __restrict__ c2b,
    const float* __restrict__ nw,  const float* __restrict__ nb,
    const float* __restrict__ niw, const float* __restrict__ nib,
    const bf16* __restrict__ wconv, const bf16* __restrict__ wkv,
    bf16* __restrict__ kbuf, bf16* __restrict__ vbuf)
{
  __shared__ bf16  Xs[64][264];   // x-tile transposed (pixel-major, c contiguous), later reused for LN'd tokens
  __shared__ float T[64][65];     // fp32 tile for epilogues

  const int bx   = blockIdx.x;
  const int tile = bx & 15;
  const int img  = (bx >> 4) & 1;
  const int b    = bx >> 5;
  const int tid  = threadIdx.x;
  const int lane = tid & 63;
  const int wvid = tid >> 6;
  const int l15  = lane & 15;
  const int quad = lane >> 4;

  // ---- stage X tile: global [c][p] coalesced -> LDS [p][c] bf16 ----
  {
    const float* xp = (img ? x2 : x1) + (size_t)b * (256 * 1024) + tile * 64;
    const int p   = tid & 63;
    const int cp0 = tid >> 6;
    #pragma unroll 4
    for (int it = 0; it < 32; ++it) {
      const int c = (cp0 + it * 4) * 2;
      const float a0 = xp[(size_t)c * 1024 + p];
      const float a1 = xp[(size_t)c * 1024 + 1024 + p];
      Xs[p][c]     = (bf16)a0;
      Xs[p][c + 1] = (bf16)a1;
    }
  }
  __syncthreads();

  // ---- conv GEMM: out[p][d] = sum_c X[p][c] * W[d][c] ----
  f32x4 acc[4] = {{0.f,0.f,0.f,0.f},{0.f,0.f,0.f,0.f},{0.f,0.f,0.f,0.f},{0.f,0.f,0.f,0.f}};
  {
    const bf16* wc = wconv + img * (64 * 256);
    #pragma unroll
    for (int k0 = 0; k0 < 256; k0 += 32) {
      const bf16x8 af = *(const bf16x8*)&Xs[wvid * 16 + l15][k0 + quad * 8];
      #pragma unroll
      for (int nt = 0; nt < 4; ++nt) {
        const bf16x8 bw = *(const bf16x8*)&wc[(nt * 16 + l15) * 256 + k0 + quad * 8];
        acc[nt] = MFMA16(af, bw, acc[nt]);
      }
    }
  }
  // bias + park in fp32 tile
  {
    const float* cb = img ? c2b : c1b;
    #pragma unroll
    for (int nt = 0; nt < 4; ++nt) {
      const int d = nt * 16 + l15;
      const float bias = cb[d];
      #pragma unroll
      for (int r = 0; r < 4; ++r)
        T[wvid * 16 + quad * 4 + r][d] = acc[nt][r] + bias;
    }
  }
  __syncthreads();

  // ---- LayerNorm(norm) then LayerNorm(ni); bf16 tokens back into Xs[p][0..63] ----
  {
    const int pix = tid >> 2, part = tid & 3;   // 4 lanes per pixel row
    float xv[16], yv[16];
    float s = 0.f, s2 = 0.f;
    #pragma unroll
    for (int i = 0; i < 16; ++i) {
      xv[i] = T[pix][part * 16 + i];
      s += xv[i]; s2 += xv[i] * xv[i];
    }
    s  += __shfl_xor(s, 1);  s  += __shfl_xor(s, 2);
    s2 += __shfl_xor(s2, 1); s2 += __shfl_xor(s2, 2);
    float mu   = s * 0.015625f;
    float rstd = rsqrtf(s2 * 0.015625f - mu * mu + 1e-5f);
    s = 0.f; s2 = 0.f;
    #pragma unroll
    for (int i = 0; i < 16; ++i) {
      const int d = part * 16 + i;
      const float y = (xv[i] - mu) * rstd * nw[d] + nb[d];
      yv[i] = y; s += y; s2 += y * y;
    }
    s  += __shfl_xor(s, 1);  s  += __shfl_xor(s, 2);
    s2 += __shfl_xor(s2, 1); s2 += __shfl_xor(s2, 2);
    mu   = s * 0.015625f;
    rstd = rsqrtf(s2 * 0.015625f - mu * mu + 1e-5f);
    #pragma unroll
    for (int i = 0; i < 16; ++i) {
      const int d = part * 16 + i;
      Xs[pix][d] = (bf16)((yv[i] - mu) * rstd * niw[d] + nib[d]);
    }
  }
  __syncthreads();

  // ---- k/v GEMMs: K=64 ----
  f32x4 ak[4] = {{0.f,0.f,0.f,0.f},{0.f,0.f,0.f,0.f},{0.f,0.f,0.f,0.f},{0.f,0.f,0.f,0.f}};
  f32x4 av[4] = {{0.f,0.f,0.f,0.f},{0.f,0.f,0.f,0.f},{0.f,0.f,0.f,0.f},{0.f,0.f,0.f,0.f}};
  #pragma unroll
  for (int k0 = 0; k0 < 64; k0 += 32) {
    const bf16x8 af = *(const bf16x8*)&Xs[wvid * 16 + l15][k0 + quad * 8];
    #pragma unroll
    for (int nt = 0; nt < 4; ++nt) {
      const bf16x8 bk = *(const bf16x8*)&wkv[(nt * 16 + l15) * 64 + k0 + quad * 8];
      const bf16x8 bv = *(const bf16x8*)&wkv[4096 + (nt * 16 + l15) * 64 + k0 + quad * 8];
      ak[nt] = MFMA16(af, bk, ak[nt]);
      av[nt] = MFMA16(af, bv, av[nt]);
    }
  }
  const size_t base = ((size_t)b * 2048 + img * 1024 + tile * 64) * 64;
  // k: repack through T for coalesced 16B stores
  __syncthreads();
  #pragma unroll
  for (int nt = 0; nt < 4; ++nt)
    #pragma unroll
    for (int r = 0; r < 4; ++r)
      T[wvid * 16 + quad * 4 + r][nt * 16 + l15] = ak[nt][r];
  __syncthreads();
  {
    const int pix = tid >> 2, dd = (tid & 3) * 16;
    bf16 tb[16];
    #pragma unroll
    for (int i = 0; i < 16; ++i) tb[i] = (bf16)T[pix][dd + i];
    *(bf16x8*)&kbuf[base + (size_t)pix * 64 + dd]     = *(bf16x8*)&tb[0];
    *(bf16x8*)&kbuf[base + (size_t)pix * 64 + dd + 8] = *(bf16x8*)&tb[8];
  }
  __syncthreads();
  #pragma unroll
  for (int nt = 0; nt < 4; ++nt)
    #pragma unroll
    for (int r = 0; r < 4; ++r)
      T[wvid * 16 + quad * 4 + r][nt * 16 + l15] = av[nt][r];
  __syncthreads();
  {
    const int pix = tid >> 2, dd = (tid & 3) * 16;
    bf16 tb[16];
    #pragma unroll
    for (int i = 0; i < 16; ++i) tb[i] = (bf16)T[pix][dd + i];
    *(bf16x8*)&vbuf[base + (size_t)pix * 64 + dd]     = *(bf16x8*)&tb[0];
    *(bf16x8*)&vbuf[base + (size_t)pix * 64 + dd + 8] = *(bf16x8*)&tb[8];
  }
}

// ---------------- K2: slot attention iterations + head ----------------
// grid 128 (one block per batch), block 512 (8 waves)
__global__ __launch_bounds__(512) void k2_slots(
    const bf16* __restrict__ kbuf, const bf16* __restrict__ vbuf,
    const float* __restrict__ smu, const float* __restrict__ slog,
    const float* __restrict__ nsw, const float* __restrict__ nsb,
    const float* __restrict__ nmw, const float* __restrict__ nmb,
    const float* __restrict__ Wq,
    const float* __restrict__ wih, const float* __restrict__ whh,
    const float* __restrict__ bih, const float* __restrict__ bhh,
    const float* __restrict__ w1,  const float* __restrict__ b1,
    const float* __restrict__ w2,  const float* __restrict__ b2,
    const float* __restrict__ hwt, const float* __restrict__ hb,
    const float* __restrict__ noise, float* __restrict__ out)
{
  __shared__ union UA { bf16 attn[2048][8]; float h1[8][128]; } ua;                       // 32 KB
  __shared__ union UB { float upd[8][8][64]; struct { float gi[8][192]; float gh[8][192]; } g; } ub; // 16 KB
  __shared__ float slots[8][64];
  __shared__ float tmp[8][64];    // sn -> updates -> h -> fused (sequential reuse)
  __shared__ bf16  qb[16][72];    // q bf16, rows 8..15 zero, padded vs bank conflicts
  __shared__ float colsum[8];
  __shared__ float mus[8], rstds[8];

  const int b    = blockIdx.x;
  const int tid  = threadIdx.x;
  const int lane = tid & 63;
  const int wvid = tid >> 6;      // 0..7
  const int l15  = lane & 15;
  const int quad = lane >> 4;
  const int s0   = tid >> 6;      // s index for 512-thread elementwise maps
  const int d0   = tid & 63;

  // init slots + zero qb pad rows (pad cols never read)
  slots[s0][d0]  = smu[d0] + expf(slog[d0]) * noise[((size_t)b * 8 + s0) * 64 + d0];
  qb[8 + s0][d0] = (bf16)0.f;
  __syncthreads();

  for (int it = 0; it < 3; ++it) {
    // LN(ns) row stats
    if (tid < 8) {
      float s = 0.f, s2 = 0.f;
      for (int d = 0; d < 64; ++d) { const float v = slots[tid][d]; s += v; s2 += v * v; }
      const float mu = s * 0.015625f;
      mus[tid]   = mu;
      rstds[tid] = rsqrtf(s2 * 0.015625f - mu * mu + 1e-5f);
      colsum[tid] = 0.f;
    }
    __syncthreads();
    tmp[s0][d0] = (slots[s0][d0] - mus[s0]) * rstds[s0] * nsw[d0] + nsb[d0];
    __syncthreads();
    // q = (sn @ Wq^T) * scale  -> bf16
    {
      float a = 0.f;
      for (int d = 0; d < 64; ++d) a += tmp[s0][d] * Wq[d0 * 64 + d];
      qb[s0][d0] = (bf16)(a * 0.125f);
    }
    __syncthreads();
    // pass 1: logits (MFMA k @ q^T), softmax over s, attn -> LDS, colsum
    {
      float cs = 0.f;
      for (int mt = 0; mt < 16; ++mt) {
        const int ntok = wvid * 256 + mt * 16;
        f32x4 lg = {0.f, 0.f, 0.f, 0.f};
        const bf16* kr = kbuf + ((size_t)b * 2048 + ntok + l15) * 64 + quad * 8;
        const bf16x8 a0 = *(const bf16x8*)&kr[0];
        const bf16x8 a1 = *(const bf16x8*)&kr[32];
        const bf16x8 q0 = *(const bf16x8*)&qb[l15][quad * 8];
        const bf16x8 q1 = *(const bf16x8*)&qb[l15][32 + quad * 8];
        lg = MFMA16(a0, q0, lg);
        lg = MFMA16(a1, q1, lg);
        #pragma unroll
        for (int r = 0; r < 4; ++r) {
          const float l = lg[r];
          float m = l;
          m = fmaxf(m, __shfl_xor(m, 1));
          m = fmaxf(m, __shfl_xor(m, 2));
          m = fmaxf(m, __shfl_xor(m, 4));
          const float e = expf(l - m);
          float ssum = e;
          ssum += __shfl_xor(ssum, 1);
          ssum += __shfl_xor(ssum, 2);
          ssum += __shfl_xor(ssum, 4);
          const float at = e / ssum + 1e-8f;
          if (l15 < 8) {
            const bf16 ab = (bf16)at;
            ua.attn[ntok + quad * 4 + r][l15] = ab;
            cs += (float)ab;      // accumulate the rounded value for consistency
          }
        }
      }
      if (l15 < 8) atomicAdd(&colsum[l15], cs);
    }
    __syncthreads();
    // pass 2: updates partials over token chunks
    {
      float acc[8] = {0.f,0.f,0.f,0.f,0.f,0.f,0.f,0.f};
      const bf16* vb = vbuf + ((size_t)b * 2048 + wvid * 256) * 64 + d0;
      for (int n = 0; n < 256; ++n) {
        const float vv = (float)vb[(size_t)n * 64];
        const bf16x8 ar = *(const bf16x8*)&ua.attn[wvid * 256 + n][0];
        #pragma unroll
        for (int s = 0; s < 8; ++s) acc[s] += (float)ar[s] * vv;
      }
      #pragma unroll
      for (int s = 0; s < 8; ++s) ub.upd[wvid][s][d0] = acc[s];
    }
    __syncthreads();
    {
      float u = 0.f;
      #pragma unroll
      for (int ch = 0; ch < 8; ++ch) u += ub.upd[ch][s0][d0];
      tmp[s0][d0] = u / colsum[s0];          // updates
    }
    __syncthreads();
    // GRU gates (overwrites ub; upd already consumed)
    for (int idx = tid; idx < 1536; idx += 512) {
      const int s = idx / 192, j = idx % 192;
      float a = bih[j], h = bhh[j];
      for (int d = 0; d < 64; ++d) {
        a += tmp[s][d]   * wih[j * 64 + d];
        h += slots[s][d] * whh[j * 64 + d];
      }
      ub.g.gi[s][j] = a;
      ub.g.gh[s][j] = h;
    }
    __syncthreads();
    {
      const float r  = 1.f / (1.f + expf(-(ub.g.gi[s0][d0]      + ub.g.gh[s0][d0])));
      const float z  = 1.f / (1.f + expf(-(ub.g.gi[s0][64 + d0] + ub.g.gh[s0][64 + d0])));
      const float nn = tanhf(ub.g.gi[s0][128 + d0] + r * ub.g.gh[s0][128 + d0]);
      slots[s0][d0] = (1.f - z) * nn + z * slots[s0][d0];
    }
    __syncthreads();
    // residual MLP
    if (tid < 8) {
      float s = 0.f, s2 = 0.f;
      for (int d = 0; d < 64; ++d) { const float v = slots[tid][d]; s += v; s2 += v * v; }
      const float mu = s * 0.015625f;
      mus[tid]   = mu;
      rstds[tid] = rsqrtf(s2 * 0.015625f - mu * mu + 1e-5f);
    }
    __syncthreads();
    tmp[s0][d0] = (slots[s0][d0] - mus[s0]) * rstds[s0] * nmw[d0] + nmb[d0];
    __syncthreads();
    for (int idx = tid; idx < 1024; idx += 512) {
      const int s = idx >> 7, j = idx & 127;
      float a = b1[j];
      for (int d = 0; d < 64; ++d) a += tmp[s][d] * w1[j * 64 + d];
      ua.h1[s][j] = fmaxf(a, 0.f);
    }
    __syncthreads();
    {
      float a = b2[d0];
      for (int j = 0; j < 128; ++j) a += ua.h1[s0][j] * w2[d0 * 128 + j];
      slots[s0][d0] += a;
    }
    __syncthreads();
  }
  // head
  if (tid < 64) {
    float f = 0.f;
    #pragma unroll
    for (int s = 0; s < 8; ++s) f += slots[s][tid];
    ((float*)tmp)[tid] = f * 0.125f;
  }
  __syncthreads();
  if (tid < 15) {
    float a = hb[tid];
    for (int d = 0; d < 64; ++d) a += ((float*)tmp)[d] * hwt[tid * 64 + d];
    out[b * 15 + tid] = a;
  }
}

extern "C" void kernel_launch(void* const* d_in, const int* in_sizes, int n_in,
                              void* d_out, int out_size, void* d_ws, size_t ws_size,
                              hipStream_t stream) {
  const float* x1   = (const float*)d_in[0];
  const float* x2   = (const float*)d_in[1];
  const float* c1w  = (const float*)d_in[2];
  const float* c1b  = (const float*)d_in[3];
  const float* c2w  = (const float*)d_in[4];
  const float* c2b  = (const float*)d_in[5];
  const float* nw   = (const float*)d_in[6];
  const float* nb   = (const float*)d_in[7];
  const float* niw  = (const float*)d_in[8];
  const float* nib  = (const float*)d_in[9];
  const float* nsw  = (const float*)d_in[10];
  const float* nsb  = (const float*)d_in[11];
  const float* nmw  = (const float*)d_in[12];
  const float* nmb  = (const float*)d_in[13];
  const float* smu  = (const float*)d_in[14];
  const float* slog = (const float*)d_in[15];
  const float* Wq   = (const float*)d_in[16];
  const float* Wk   = (const float*)d_in[17];
  const float* Wv   = (const float*)d_in[18];
  const float* wih  = (const float*)d_in[19];
  const float* whh  = (const float*)d_in[20];
  const float* bih  = (const float*)d_in[21];
  const float* bhh  = (const float*)d_in[22];
  const float* w1   = (const float*)d_in[23];
  const float* b1   = (const float*)d_in[24];
  const float* w2   = (const float*)d_in[25];
  const float* b2   = (const float*)d_in[26];
  const float* hwt  = (const float*)d_in[27];
  const float* hb   = (const float*)d_in[28];
  const float* noise= (const float*)d_in[29];

  char* ws = (char*)d_ws;
  bf16* kbuf  = (bf16*)(ws);
  bf16* vbuf  = (bf16*)(ws + (size_t)33554432);
  bf16* wconv = (bf16*)(ws + (size_t)67108864);
  bf16* wkv   = (bf16*)(ws + (size_t)67174400);

  k0_convert<<<dim3(64), dim3(256), 0, stream>>>(c1w, c2w, Wk, Wv, wconv, wkv);
  k1_conv_kv<<<dim3(4096), dim3(256), 0, stream>>>(x1, x2, c1b, c2b, nw, nb, niw, nib,
                                                   wconv, wkv, kbuf, vbuf);
  k2_slots<<<dim3(128), dim3(512), 0, stream>>>(kbuf, vbuf, smu, slog, nsw, nsb, nmw, nmb, Wq,
                                                wih, whh, bih, bhh, w1, b1, w2, b2, hwt, hb,
                                                noise, (float*)d_out);
}

// Round 2
// 608.969 us; speedup vs baseline: 1.0575x; 1.0575x over previous
//
#include <hip/hip_runtime.h>
#include <stdint.h>

// JointSlotFusion on MI355X (gfx950).
// ws layout (bytes):
//   kbuf   bf16[128][2048][64]   @ 0          (33,554,432)
//   vbuf   bf16[128][2048][64]   @ 33,554,432 (33,554,432)
//   wconv  bf16[2][64][256]      @ 67,108,864 (65,536)
//   wkv    bf16[2][64][64]       @ 67,174,400 (16,384)
//   slotbuf f32[128][8][64]      @ 67,190,784 (262,144)
//   qbuf   bf16[128][8][64]      @ 67,452,928 (131,072)
//   updpart f32[128][16][8][64]  @ 67,584,000 (4,194,304)
//   colpart f32[128][16][8]      @ 71,778,304 (65,536)
// total 71,843,840 B

typedef __bf16 bf16;
typedef __bf16 bf16x8 __attribute__((ext_vector_type(8)));
typedef float  f32x4  __attribute__((ext_vector_type(4)));

#define MFMA16(a, b, c) __builtin_amdgcn_mfma_f32_16x16x32_bf16((a), (b), (c), 0, 0, 0)

#define ASYNC_LDS16(g, l) \
  __builtin_amdgcn_global_load_lds((const __attribute__((address_space(1))) void*)(g), \
                                   (__attribute__((address_space(3))) void*)(l), 16, 0, 0)

// ---------------- K0: weight fp32 -> bf16 ----------------
__global__ __launch_bounds__(256) void k0_convert(
    const float* __restrict__ c1w, const float* __restrict__ c2w,
    const float* __restrict__ wk,  const float* __restrict__ wvv,
    bf16* __restrict__ wconv, bf16* __restrict__ wkv)
{
  const int i = blockIdx.x * 256 + threadIdx.x;   // 64 blocks
  if (i < 16384) {
    wconv[i]         = (bf16)c1w[i];
    wconv[16384 + i] = (bf16)c2w[i];
  }
  if (i < 4096) {
    wkv[i]        = (bf16)wk[i];
    wkv[4096 + i] = (bf16)wvv[i];
  }
}

// ---------------- K1: conv1x1 + LN + LN + k/v GEMM ----------------
// grid 4096 = 128 b * 2 img * 16 pixel-tiles of 64; block 256 (4 waves)
// X staged fp32 via async global_load_lds: 4-row groups of 64 px, group g = c>>2
// at xs[g*264]; element (c,p) at g*264 + (c&3)*64 + p. Group pad = 8 floats
// keeps MFMA A-fragment ds_read_b32 pattern at <=2 lanes/bank (free, m136).
__global__ __launch_bounds__(256) void k1_conv_kv(
    const float* __restrict__ x1, const float* __restrict__ x2,
    const float* __restrict__ c1b, const float* __restrict__ c2b,
    const float* __restrict__ nw,  const float* __restrict__ nb,
    const float* __restrict__ niw, const float* __restrict__ nib,
    const bf16* __restrict__ wconv, const bf16* __restrict__ wkv,
    bf16* __restrict__ kbuf, bf16* __restrict__ vbuf)
{
  __shared__ union {
    float xs[64 * 264];                               // 67,584 B (phase 1)
    struct { float T[64][65]; bf16 tok[64][72]; } p2; // 25,856 B (phase 2+)
  } U;

  const int bx   = blockIdx.x;
  const int tile = bx & 15;
  const int img  = (bx >> 4) & 1;
  const int b    = bx >> 5;
  const int tid  = threadIdx.x;
  const int lane = tid & 63;
  const int wvid = tid >> 6;
  const int l15  = lane & 15;
  const int quad = lane >> 4;

  // ---- async stage: global [c][1024] window -> LDS fp32 grouped layout ----
  {
    const float* xp = (img ? x2 : x1) + (size_t)b * (256 * 1024) + tile * 64;
    const int rowin = lane >> 4;            // c&3 within group
    const int pq    = (lane & 15) * 4;      // 4 px per lane
    const float* ga0 = xp + (size_t)rowin * 1024 + pq;
    #pragma unroll
    for (int gi = 0; gi < 16; ++gi) {
      const int g = wvid + gi * 4;          // each wave: 16 groups of 4 rows
      ASYNC_LDS16(ga0 + (size_t)g * 4096, &U.xs[g * 264]);
    }
  }
  __syncthreads();

  // ---- conv GEMM: out[p][d] = sum_c X[p][c] * W[d][c] ----
  f32x4 acc[4] = {{0.f,0.f,0.f,0.f},{0.f,0.f,0.f,0.f},{0.f,0.f,0.f,0.f},{0.f,0.f,0.f,0.f}};
  {
    const bf16* wc = wconv + img * (64 * 256);
    const int p = wvid * 16 + l15;
    #pragma unroll
    for (int k0 = 0; k0 < 256; k0 += 32) {
      bf16x8 af;
      #pragma unroll
      for (int j = 0; j < 8; ++j) {
        const int c = k0 + quad * 8 + j;
        af[j] = (bf16)U.xs[(c >> 2) * 264 + (c & 3) * 64 + p];
      }
      #pragma unroll
      for (int nt = 0; nt < 4; ++nt) {
        const bf16x8 bw = *(const bf16x8*)&wc[(nt * 16 + l15) * 256 + k0 + quad * 8];
        acc[nt] = MFMA16(af, bw, acc[nt]);
      }
    }
  }
  __syncthreads();   // xs dead -> p2 region live

  // bias + park in fp32 tile
  {
    const float* cb = img ? c2b : c1b;
    #pragma unroll
    for (int nt = 0; nt < 4; ++nt) {
      const int d = nt * 16 + l15;
      const float bias = cb[d];
      #pragma unroll
      for (int r = 0; r < 4; ++r)
        U.p2.T[wvid * 16 + quad * 4 + r][d] = acc[nt][r] + bias;
    }
  }
  __syncthreads();

  // ---- LayerNorm(norm) then LayerNorm(ni); bf16 tokens into tok ----
  {
    const int pix = tid >> 2, part = tid & 3;   // 4 lanes per pixel row
    float xv[16], yv[16];
    float s = 0.f, s2 = 0.f;
    #pragma unroll
    for (int i = 0; i < 16; ++i) {
      xv[i] = U.p2.T[pix][part * 16 + i];
      s += xv[i]; s2 += xv[i] * xv[i];
    }
    s  += __shfl_xor(s, 1);  s  += __shfl_xor(s, 2);
    s2 += __shfl_xor(s2, 1); s2 += __shfl_xor(s2, 2);
    float mu   = s * 0.015625f;
    float rstd = rsqrtf(s2 * 0.015625f - mu * mu + 1e-5f);
    s = 0.f; s2 = 0.f;
    #pragma unroll
    for (int i = 0; i < 16; ++i) {
      const int d = part * 16 + i;
      const float y = (xv[i] - mu) * rstd * nw[d] + nb[d];
      yv[i] = y; s += y; s2 += y * y;
    }
    s  += __shfl_xor(s, 1);  s  += __shfl_xor(s, 2);
    s2 += __shfl_xor(s2, 1); s2 += __shfl_xor(s2, 2);
    mu   = s * 0.015625f;
    rstd = rsqrtf(s2 * 0.015625f - mu * mu + 1e-5f);
    #pragma unroll
    for (int i = 0; i < 16; ++i) {
      const int d = part * 16 + i;
      U.p2.tok[pix][d] = (bf16)((yv[i] - mu) * rstd * niw[d] + nib[d]);
    }
  }
  __syncthreads();

  // ---- k/v GEMMs: K=64 ----
  f32x4 ak[4] = {{0.f,0.f,0.f,0.f},{0.f,0.f,0.f,0.f},{0.f,0.f,0.f,0.f},{0.f,0.f,0.f,0.f}};
  f32x4 av[4] = {{0.f,0.f,0.f,0.f},{0.f,0.f,0.f,0.f},{0.f,0.f,0.f,0.f},{0.f,0.f,0.f,0.f}};
  #pragma unroll
  for (int k0 = 0; k0 < 64; k0 += 32) {
    const bf16x8 af = *(const bf16x8*)&U.p2.tok[wvid * 16 + l15][k0 + quad * 8];
    #pragma unroll
    for (int nt = 0; nt < 4; ++nt) {
      const bf16x8 bk = *(const bf16x8*)&wkv[(nt * 16 + l15) * 64 + k0 + quad * 8];
      const bf16x8 bv = *(const bf16x8*)&wkv[4096 + (nt * 16 + l15) * 64 + k0 + quad * 8];
      ak[nt] = MFMA16(af, bk, ak[nt]);
      av[nt] = MFMA16(af, bv, av[nt]);
    }
  }
  const size_t base = ((size_t)b * 2048 + img * 1024 + tile * 64) * 64;
  __syncthreads();
  #pragma unroll
  for (int nt = 0; nt < 4; ++nt)
    #pragma unroll
    for (int r = 0; r < 4; ++r)
      U.p2.T[wvid * 16 + quad * 4 + r][nt * 16 + l15] = ak[nt][r];
  __syncthreads();
  {
    const int pix = tid >> 2, dd = (tid & 3) * 16;
    bf16 tb[16];
    #pragma unroll
    for (int i = 0; i < 16; ++i) tb[i] = (bf16)U.p2.T[pix][dd + i];
    *(bf16x8*)&kbuf[base + (size_t)pix * 64 + dd]     = *(bf16x8*)&tb[0];
    *(bf16x8*)&kbuf[base + (size_t)pix * 64 + dd + 8] = *(bf16x8*)&tb[8];
  }
  __syncthreads();
  #pragma unroll
  for (int nt = 0; nt < 4; ++nt)
    #pragma unroll
    for (int r = 0; r < 4; ++r)
      U.p2.T[wvid * 16 + quad * 4 + r][nt * 16 + l15] = av[nt][r];
  __syncthreads();
  {
    const int pix = tid >> 2, dd = (tid & 3) * 16;
    bf16 tb[16];
    #pragma unroll
    for (int i = 0; i < 16; ++i) tb[i] = (bf16)U.p2.T[pix][dd + i];
    *(bf16x8*)&vbuf[base + (size_t)pix * 64 + dd]     = *(bf16x8*)&tb[0];
    *(bf16x8*)&vbuf[base + (size_t)pix * 64 + dd + 8] = *(bf16x8*)&tb[8];
  }
}

// ---------------- kS0: slots init + q0 ----------------
__global__ __launch_bounds__(512) void kS0(
    const float* __restrict__ smu, const float* __restrict__ slog,
    const float* __restrict__ noise,
    const float* __restrict__ nsw, const float* __restrict__ nsb,
    const float* __restrict__ Wq,
    float* __restrict__ slotbuf, bf16* __restrict__ qbuf)
{
  __shared__ float slots[8][64], tmp[8][64], mus[8], rstds[8];
  const int b = blockIdx.x, tid = threadIdx.x;
  const int s0 = tid >> 6, d0 = tid & 63;
  const float sv = smu[d0] + expf(slog[d0]) * noise[((size_t)b * 8 + s0) * 64 + d0];
  slots[s0][d0] = sv;
  slotbuf[((size_t)b * 8 + s0) * 64 + d0] = sv;
  __syncthreads();
  if (tid < 8) {
    float s = 0.f, s2 = 0.f;
    for (int d = 0; d < 64; ++d) { const float v = slots[tid][d]; s += v; s2 += v * v; }
    const float mu = s * 0.015625f;
    mus[tid] = mu;
    rstds[tid] = rsqrtf(s2 * 0.015625f - mu * mu + 1e-5f);
  }
  __syncthreads();
  tmp[s0][d0] = (slots[s0][d0] - mus[s0]) * rstds[s0] * nsw[d0] + nsb[d0];
  __syncthreads();
  float a = 0.f;
  for (int d = 0; d < 64; ++d) a += tmp[s0][d] * Wq[d0 * 64 + d];
  qbuf[((size_t)b * 8 + s0) * 64 + d0] = (bf16)(a * 0.125f);
}

// ---------------- kA: logits + softmax + partial updates/colsum ----------------
// grid 2048 = 128 b * 16 chunks of 128 tokens; block 256 (4 waves)
__global__ __launch_bounds__(256) void kA(
    const bf16* __restrict__ kbuf, const bf16* __restrict__ vbuf,
    const bf16* __restrict__ qbuf,
    float* __restrict__ updpart, float* __restrict__ colpart)
{
  __shared__ bf16  qs[16][72];     // q rows 0..7, rows 8..15 zero
  __shared__ bf16  vs[128][64];    // 16 KB v chunk
  __shared__ float attn[8][132];   // [s][token] fp32, padded
  __shared__ float cspart[4][8];

  const int bx  = blockIdx.x;
  const int b   = bx >> 4, ch = bx & 15;
  const int tid = threadIdx.x;
  const int lane = tid & 63;
  const int wvid = tid >> 6;       // 0..3
  const int l15  = lane & 15;
  const int quad = lane >> 4;
  const size_t tokbase = (size_t)b * 2048 + ch * 128;

  // stage v (coalesced 16B/lane) and q
  {
    const bf16* vg = vbuf + tokbase * 64;
    bf16* vsf = &vs[0][0];
    #pragma unroll
    for (int r = 0; r < 4; ++r) {
      const int idx = r * 256 + tid;
      *(bf16x8*)&vsf[idx * 8] = *(const bf16x8*)&vg[idx * 8];
    }
    if (tid < 64) {
      const int s = tid >> 3, o = (tid & 7) * 8;
      *(bf16x8*)&qs[s][o] = *(const bf16x8*)&qbuf[((size_t)b * 8 + s) * 64 + o];
    } else if (tid < 128) {
      const int s = 8 + ((tid - 64) >> 3), o = ((tid - 64) & 7) * 8;
      uint32_t* zp = (uint32_t*)&qs[s][o];
      zp[0] = 0u; zp[1] = 0u; zp[2] = 0u; zp[3] = 0u;
    }
  }
  __syncthreads();

  // logits via MFMA (A = k rows from global, B = q in LDS), softmax over s=8
  {
    float cs = 0.f;
    #pragma unroll
    for (int ms = 0; ms < 2; ++ms) {
      const int t0 = wvid * 32 + ms * 16;
      const bf16* kr = kbuf + (tokbase + t0 + l15) * 64 + quad * 8;
      f32x4 lg = {0.f, 0.f, 0.f, 0.f};
      lg = MFMA16(*(const bf16x8*)&kr[0],  *(const bf16x8*)&qs[l15][quad * 8],      lg);
      lg = MFMA16(*(const bf16x8*)&kr[32], *(const bf16x8*)&qs[l15][32 + quad * 8], lg);
      #pragma unroll
      for (int r = 0; r < 4; ++r) {
        const float l = lg[r];
        float m = l;
        m = fmaxf(m, __shfl_xor(m, 1));
        m = fmaxf(m, __shfl_xor(m, 2));
        m = fmaxf(m, __shfl_xor(m, 4));
        const float e = expf(l - m);
        float ss = e;
        ss += __shfl_xor(ss, 1);
        ss += __shfl_xor(ss, 2);
        ss += __shfl_xor(ss, 4);
        const float at = e / ss + 1e-8f;
        if (l15 < 8) { attn[l15][t0 + quad * 4 + r] = at; cs += at; }
      }
    }
    cs += __shfl_xor(cs, 16);
    cs += __shfl_xor(cs, 32);
    if (lane < 8) cspart[wvid][lane] = cs;
  }
  __syncthreads();

  // updates: u[s][d] = sum_n attn[s][n] * v[n][d]  (attn read is wave-uniform broadcast)
  {
    const int d0 = tid & 63;
    const int sA = tid >> 6;        // s = sA and sA+4
    float u0 = 0.f, u1 = 0.f;
    #pragma unroll 4
    for (int n = 0; n < 128; ++n) {
      const float vv = (float)vs[n][d0];
      u0 += attn[sA][n] * vv;
      u1 += attn[sA + 4][n] * vv;
    }
    float* up = updpart + ((size_t)b * 16 + ch) * 512;
    up[sA * 64 + d0]       = u0;
    up[(sA + 4) * 64 + d0] = u1;
    if (tid < 8)
      colpart[((size_t)b * 16 + ch) * 8 + tid] =
        cspart[0][tid] + cspart[1][tid] + cspart[2][tid] + cspart[3][tid];
  }
}

// ---------------- kB: reduce + GRU + MLP + next-q / head ----------------
// grid 128, block 512
__global__ __launch_bounds__(512) void kB(
    const float* __restrict__ updpart, const float* __restrict__ colpart,
    float* __restrict__ slotbuf, bf16* __restrict__ qbuf,
    const float* __restrict__ nsw, const float* __restrict__ nsb,
    const float* __restrict__ nmw, const float* __restrict__ nmb,
    const float* __restrict__ Wq,
    const float* __restrict__ wih, const float* __restrict__ whh,
    const float* __restrict__ bih, const float* __restrict__ bhh,
    const float* __restrict__ w1,  const float* __restrict__ b1,
    const float* __restrict__ w2,  const float* __restrict__ b2,
    const float* __restrict__ hwt, const float* __restrict__ hb,
    float* __restrict__ out, const int last)
{
  __shared__ float slots[8][64], tmp[8][64];
  __shared__ union { float h1[8][128]; struct { float gi[8][192]; float gh[8][192]; } g; } ub;
  __shared__ float mus[8], rstds[8];
  const int b = blockIdx.x, tid = threadIdx.x;
  const int s0 = tid >> 6, d0 = tid & 63;

  {
    const float* up = updpart + (size_t)b * 16 * 512;
    float u = 0.f;
    #pragma unroll
    for (int ch = 0; ch < 16; ++ch) u += up[ch * 512 + s0 * 64 + d0];
    const float* cp = colpart + (size_t)b * 128;
    float cs = 0.f;
    #pragma unroll
    for (int ch = 0; ch < 16; ++ch) cs += cp[ch * 8 + s0];
    tmp[s0][d0] = u / cs;                                   // updates
    slots[s0][d0] = slotbuf[((size_t)b * 8 + s0) * 64 + d0]; // slots_prev
  }
  __syncthreads();

  // GRU gates
  for (int idx = tid; idx < 1536; idx += 512) {
    const int s = idx / 192, j = idx % 192;
    float a = bih[j], h = bhh[j];
    for (int d = 0; d < 64; ++d) {
      a += tmp[s][d]   * wih[j * 64 + d];
      h += slots[s][d] * whh[j * 64 + d];
    }
    ub.g.gi[s][j] = a;
    ub.g.gh[s][j] = h;
  }
  __syncthreads();
  {
    const float r  = 1.f / (1.f + expf(-(ub.g.gi[s0][d0]       + ub.g.gh[s0][d0])));
    const float z  = 1.f / (1.f + expf(-(ub.g.gi[s0][64 + d0]  + ub.g.gh[s0][64 + d0])));
    const float nn = tanhf(ub.g.gi[s0][128 + d0] + r * ub.g.gh[s0][128 + d0]);
    slots[s0][d0] = (1.f - z) * nn + z * slots[s0][d0];
  }
  __syncthreads();

  // residual MLP
  if (tid < 8) {
    float s = 0.f, s2 = 0.f;
    for (int d = 0; d < 64; ++d) { const float v = slots[tid][d]; s += v; s2 += v * v; }
    const float mu = s * 0.015625f;
    mus[tid] = mu;
    rstds[tid] = rsqrtf(s2 * 0.015625f - mu * mu + 1e-5f);
  }
  __syncthreads();
  tmp[s0][d0] = (slots[s0][d0] - mus[s0]) * rstds[s0] * nmw[d0] + nmb[d0];
  __syncthreads();
  for (int idx = tid; idx < 1024; idx += 512) {
    const int s = idx >> 7, j = idx & 127;
    float a = b1[j];
    for (int d = 0; d < 64; ++d) a += tmp[s][d] * w1[j * 64 + d];
    ub.h1[s][j] = fmaxf(a, 0.f);
  }
  __syncthreads();
  {
    float a = b2[d0];
    for (int j = 0; j < 128; ++j) a += ub.h1[s0][j] * w2[d0 * 128 + j];
    slots[s0][d0] += a;
  }
  __syncthreads();

  slotbuf[((size_t)b * 8 + s0) * 64 + d0] = slots[s0][d0];

  if (!last) {
    // q for next iteration: LN(ns) + @Wq^T * scale
    if (tid < 8) {
      float s = 0.f, s2 = 0.f;
      for (int d = 0; d < 64; ++d) { const float v = slots[tid][d]; s += v; s2 += v * v; }
      const float mu = s * 0.015625f;
      mus[tid] = mu;
      rstds[tid] = rsqrtf(s2 * 0.015625f - mu * mu + 1e-5f);
    }
    __syncthreads();
    tmp[s0][d0] = (slots[s0][d0] - mus[s0]) * rstds[s0] * nsw[d0] + nsb[d0];
    __syncthreads();
    float a = 0.f;
    for (int d = 0; d < 64; ++d) a += tmp[s0][d] * Wq[d0 * 64 + d];
    qbuf[((size_t)b * 8 + s0) * 64 + d0] = (bf16)(a * 0.125f);
  } else {
    // head
    if (tid < 64) {
      float f = 0.f;
      #pragma unroll
      for (int s = 0; s < 8; ++s) f += slots[s][tid];
      ((float*)tmp)[tid] = f * 0.125f;
    }
    __syncthreads();
    if (tid < 15) {
      float a = hb[tid];
      for (int d = 0; d < 64; ++d) a += ((float*)tmp)[d] * hwt[tid * 64 + d];
      out[b * 15 + tid] = a;
    }
  }
}

extern "C" void kernel_launch(void* const* d_in, const int* in_sizes, int n_in,
                              void* d_out, int out_size, void* d_ws, size_t ws_size,
                              hipStream_t stream) {
  const float* x1   = (const float*)d_in[0];
  const float* x2   = (const float*)d_in[1];
  const float* c1w  = (const float*)d_in[2];
  const float* c1b  = (const float*)d_in[3];
  const float* c2w  = (const float*)d_in[4];
  const float* c2b  = (const float*)d_in[5];
  const float* nw   = (const float*)d_in[6];
  const float* nb   = (const float*)d_in[7];
  const float* niw  = (const float*)d_in[8];
  const float* nib  = (const float*)d_in[9];
  const float* nsw  = (const float*)d_in[10];
  const float* nsb  = (const float*)d_in[11];
  const float* nmw  = (const float*)d_in[12];
  const float* nmb  = (const float*)d_in[13];
  const float* smu  = (const float*)d_in[14];
  const float* slog = (const float*)d_in[15];
  const float* Wq   = (const float*)d_in[16];
  const float* Wk   = (const float*)d_in[17];
  const float* Wv   = (const float*)d_in[18];
  const float* wih  = (const float*)d_in[19];
  const float* whh  = (const float*)d_in[20];
  const float* bih  = (const float*)d_in[21];
  const float* bhh  = (const float*)d_in[22];
  const float* w1   = (const float*)d_in[23];
  const float* b1   = (const float*)d_in[24];
  const float* w2   = (const float*)d_in[25];
  const float* b2   = (const float*)d_in[26];
  const float* hwt  = (const float*)d_in[27];
  const float* hb   = (const float*)d_in[28];
  const float* noise= (const float*)d_in[29];

  char* ws = (char*)d_ws;
  bf16*  kbuf    = (bf16*)(ws);
  bf16*  vbuf    = (bf16*)(ws + (size_t)33554432);
  bf16*  wconv   = (bf16*)(ws + (size_t)67108864);
  bf16*  wkv     = (bf16*)(ws + (size_t)67174400);
  float* slotbuf = (float*)(ws + (size_t)67190784);
  bf16*  qbuf    = (bf16*)(ws + (size_t)67452928);
  float* updpart = (float*)(ws + (size_t)67584000);
  float* colpart = (float*)(ws + (size_t)71778304);

  k0_convert<<<dim3(64), dim3(256), 0, stream>>>(c1w, c2w, Wk, Wv, wconv, wkv);
  k1_conv_kv<<<dim3(4096), dim3(256), 0, stream>>>(x1, x2, c1b, c2b, nw, nb, niw, nib,
                                                   wconv, wkv, kbuf, vbuf);
  kS0<<<dim3(128), dim3(512), 0, stream>>>(smu, slog, noise, nsw, nsb, Wq, slotbuf, qbuf);
  for (int it = 0; it < 3; ++it) {
    kA<<<dim3(2048), dim3(256), 0, stream>>>(kbuf, vbuf, qbuf, updpart, colpart);
    kB<<<dim3(128), dim3(512), 0, stream>>>(updpart, colpart, slotbuf, qbuf,
                                            nsw, nsb, nmw, nmb, Wq,
                                            wih, whh, bih, bhh, w1, b1, w2, b2,
                                            hwt, hb, (float*)d_out, (it == 2) ? 1 : 0);
  }
}

// Round 4
// 523.892 us; speedup vs baseline: 1.2293x; 1.1624x over previous
//
#include <hip/hip_runtime.h>
#include <stdint.h>

// JointSlotFusion on MI355X (gfx950).
// ws layout (bytes):
//   kbuf   bf16[128][2048][64]   @ 0          (33,554,432)   token-major
//   vT     bf16[128][64][2048]   @ 33,554,432 (33,554,432)   d-major (transposed)
//   wconv  bf16[2][64][256]      @ 67,108,864 (65,536)
//   wkv    bf16[2][64][64]       @ 67,174,400 (16,384)
//   slotbuf f32[128][8][64]      @ 67,190,784 (262,144)
//   qbuf   bf16[128][8][64]      @ 67,452,928 (131,072)
//   updpart f32[128][16][8][64]  @ 67,584,000 (4,194,304)
//   colpart f32[128][16][8]      @ 71,778,304 (65,536)

typedef __bf16 bf16;
typedef __bf16 bf16x8 __attribute__((ext_vector_type(8)));
typedef float  f32x4  __attribute__((ext_vector_type(4)));

#define MFMA16(a, b, c) __builtin_amdgcn_mfma_f32_16x16x32_bf16((a), (b), (c), 0, 0, 0)

#define ASYNC_LDS16(g, l) \
  __builtin_amdgcn_global_load_lds((const __attribute__((address_space(1))) void*)(g), \
                                   (__attribute__((address_space(3))) void*)(l), 16, 0, 0)

// ---------------- K0: weight fp32 -> bf16 ----------------
__global__ __launch_bounds__(256) void k0_convert(
    const float* __restrict__ c1w, const float* __restrict__ c2w,
    const float* __restrict__ wk,  const float* __restrict__ wvv,
    bf16* __restrict__ wconv, bf16* __restrict__ wkv)
{
  const int i = blockIdx.x * 256 + threadIdx.x;   // 64 blocks
  if (i < 16384) {
    wconv[i]         = (bf16)c1w[i];
    wconv[16384 + i] = (bf16)c2w[i];
  }
  if (i < 4096) {
    wkv[i]        = (bf16)wk[i];
    wkv[4096 + i] = (bf16)wvv[i];
  }
}

// ---------------- K1: conv1x1 + LN + LN + k/v GEMM ----------------
// grid 4096 = 128 b * 2 img * 16 pixel-tiles of 64; block 256 (4 waves)
// K staged in 2 halves of 128 channels reusing one 33.8 KB buffer -> 4 blocks/CU.
__global__ __launch_bounds__(256) void k1_conv_kv(
    const float* __restrict__ x1, const float* __restrict__ x2,
    const float* __restrict__ c1b, const float* __restrict__ c2b,
    const float* __restrict__ nw,  const float* __restrict__ nb,
    const float* __restrict__ niw, const float* __restrict__ nib,
    const bf16* __restrict__ wconv, const bf16* __restrict__ wkv,
    bf16* __restrict__ kbuf, bf16* __restrict__ vT)
{
  __shared__ union {
    float xs[32 * 264];                               // 33,792 B staging (one K-half)
    struct { float T[64][65]; bf16 tok[64][72]; } p2; // 25,856 B
    struct { float Tk[64][65]; float Tv[64][65]; } kv;// 33,280 B
  } U;

  const int bx   = blockIdx.x;
  const int tile = bx & 15;
  const int img  = (bx >> 4) & 1;
  const int b    = bx >> 5;
  const int tid  = threadIdx.x;
  const int lane = tid & 63;
  const int wvid = tid >> 6;
  const int l15  = lane & 15;
  const int quad = lane >> 4;

  const float* xp  = (img ? x2 : x1) + (size_t)b * (256 * 1024) + tile * 64;
  const int   rowin = lane >> 4;
  const int   pq    = (lane & 15) * 4;
  const float* ga0  = xp + (size_t)rowin * 1024 + pq;
  const bf16* wc = wconv + img * (64 * 256);
  const int p = wvid * 16 + l15;

  f32x4 acc[4] = {{0.f,0.f,0.f,0.f},{0.f,0.f,0.f,0.f},{0.f,0.f,0.f,0.f},{0.f,0.f,0.f,0.f}};

  for (int half = 0; half < 2; ++half) {
    // stage: 32 groups of (4 channels x 64 px), group g at xs[g*264]
    #pragma unroll
    for (int gi = 0; gi < 8; ++gi) {
      const int g = wvid + gi * 4;
      ASYNC_LDS16(ga0 + (size_t)(half * 128 + g * 4) * 1024, &U.xs[g * 264]);
    }
    __syncthreads();
    #pragma unroll
    for (int k0 = 0; k0 < 128; k0 += 32) {
      bf16x8 af;
      #pragma unroll
      for (int j = 0; j < 8; ++j) {
        const int c = k0 + quad * 8 + j;
        af[j] = (bf16)U.xs[(c >> 2) * 264 + (c & 3) * 64 + p];
      }
      #pragma unroll
      for (int nt = 0; nt < 4; ++nt) {
        const bf16x8 bw = *(const bf16x8*)&wc[(nt * 16 + l15) * 256 + half * 128 + k0 + quad * 8];
        acc[nt] = MFMA16(af, bw, acc[nt]);
      }
    }
    __syncthreads();   // xs reads done before restage / p2 reuse
  }

  // bias + park in fp32 tile
  {
    const float* cb = img ? c2b : c1b;
    #pragma unroll
    for (int nt = 0; nt < 4; ++nt) {
      const int d = nt * 16 + l15;
      const float bias = cb[d];
      #pragma unroll
      for (int r = 0; r < 4; ++r)
        U.p2.T[wvid * 16 + quad * 4 + r][d] = acc[nt][r] + bias;
    }
  }
  __syncthreads();

  // Double LayerNorm -> bf16 tokens
  {
    const int pix = tid >> 2, part = tid & 3;
    float xv[16], yv[16];
    float s = 0.f, s2 = 0.f;
    #pragma unroll
    for (int i = 0; i < 16; ++i) {
      xv[i] = U.p2.T[pix][part * 16 + i];
      s += xv[i]; s2 += xv[i] * xv[i];
    }
    s  += __shfl_xor(s, 1);  s  += __shfl_xor(s, 2);
    s2 += __shfl_xor(s2, 1); s2 += __shfl_xor(s2, 2);
    float mu   = s * 0.015625f;
    float rstd = rsqrtf(s2 * 0.015625f - mu * mu + 1e-5f);
    s = 0.f; s2 = 0.f;
    #pragma unroll
    for (int i = 0; i < 16; ++i) {
      const int d = part * 16 + i;
      const float y = (xv[i] - mu) * rstd * nw[d] + nb[d];
      yv[i] = y; s += y; s2 += y * y;
    }
    s  += __shfl_xor(s, 1);  s  += __shfl_xor(s, 2);
    s2 += __shfl_xor(s2, 1); s2 += __shfl_xor(s2, 2);
    mu   = s * 0.015625f;
    rstd = rsqrtf(s2 * 0.015625f - mu * mu + 1e-5f);
    #pragma unroll
    for (int i = 0; i < 16; ++i) {
      const int d = part * 16 + i;
      U.p2.tok[pix][d] = (bf16)((yv[i] - mu) * rstd * niw[d] + nib[d]);
    }
  }
  __syncthreads();

  // k/v GEMMs: K=64
  f32x4 ak[4] = {{0.f,0.f,0.f,0.f},{0.f,0.f,0.f,0.f},{0.f,0.f,0.f,0.f},{0.f,0.f,0.f,0.f}};
  f32x4 av[4] = {{0.f,0.f,0.f,0.f},{0.f,0.f,0.f,0.f},{0.f,0.f,0.f,0.f},{0.f,0.f,0.f,0.f}};
  #pragma unroll
  for (int k0 = 0; k0 < 64; k0 += 32) {
    const bf16x8 af = *(const bf16x8*)&U.p2.tok[wvid * 16 + l15][k0 + quad * 8];
    #pragma unroll
    for (int nt = 0; nt < 4; ++nt) {
      const bf16x8 bk = *(const bf16x8*)&wkv[(nt * 16 + l15) * 64 + k0 + quad * 8];
      const bf16x8 bv = *(const bf16x8*)&wkv[4096 + (nt * 16 + l15) * 64 + k0 + quad * 8];
      ak[nt] = MFMA16(af, bk, ak[nt]);
      av[nt] = MFMA16(af, bv, av[nt]);
    }
  }
  __syncthreads();   // tok read done -> kv region live

  // repack both k (pixel-major) and v (d-major) in one barrier pair
  #pragma unroll
  for (int nt = 0; nt < 4; ++nt)
    #pragma unroll
    for (int r = 0; r < 4; ++r) {
      U.kv.Tk[wvid * 16 + quad * 4 + r][nt * 16 + l15] = ak[nt][r];
      U.kv.Tv[nt * 16 + l15][wvid * 16 + quad * 4 + r] = av[nt][r];
    }
  __syncthreads();
  {
    const int row = tid >> 2, dd = (tid & 3) * 16;
    const size_t kb = ((size_t)b * 2048 + img * 1024 + tile * 64) * 64;
    bf16 tb[16];
    #pragma unroll
    for (int i = 0; i < 16; ++i) tb[i] = (bf16)U.kv.Tk[row][dd + i];
    *(bf16x8*)&kbuf[kb + (size_t)row * 64 + dd]     = *(bf16x8*)&tb[0];
    *(bf16x8*)&kbuf[kb + (size_t)row * 64 + dd + 8] = *(bf16x8*)&tb[8];
    #pragma unroll
    for (int i = 0; i < 16; ++i) tb[i] = (bf16)U.kv.Tv[row][dd + i];
    const size_t vb = ((size_t)b * 64 + row) * 2048 + img * 1024 + tile * 64 + dd;
    *(bf16x8*)&vT[vb]     = *(bf16x8*)&tb[0];
    *(bf16x8*)&vT[vb + 8] = *(bf16x8*)&tb[8];
  }
}

// ---------------- kS0: slots init + q0 ----------------
__global__ __launch_bounds__(512) void kS0(
    const float* __restrict__ smu, const float* __restrict__ slog,
    const float* __restrict__ noise,
    const float* __restrict__ nsw, const float* __restrict__ nsb,
    const float* __restrict__ Wq,
    float* __restrict__ slotbuf, bf16* __restrict__ qbuf)
{
  __shared__ float tmp[8][66];
  const int b = blockIdx.x, tid = threadIdx.x;
  const int s0 = tid >> 6, d0 = tid & 63;
  const int part = tid & 7, sl = (tid >> 3) & 7, wv = tid >> 6;

  const float sval = smu[d0] + expf(slog[d0]) * noise[((size_t)b * 8 + s0) * 64 + d0];
  slotbuf[((size_t)b * 8 + s0) * 64 + d0] = sval;
  float s = sval, s2 = sval * sval;
  #pragma unroll
  for (int m = 1; m < 64; m <<= 1) { s += __shfl_xor(s, m); s2 += __shfl_xor(s2, m); }
  const float mu = s * 0.015625f;
  const float rstd = rsqrtf(s2 * 0.015625f - mu * mu + 1e-5f);
  tmp[s0][d0] = (sval - mu) * rstd * nsw[d0] + nsb[d0];
  __syncthreads();

  float tm[8];
  #pragma unroll
  for (int i = 0; i < 8; ++i) tm[i] = tmp[sl][part * 8 + i];
  for (int orr = 0; orr < 8; ++orr) {
    const int d = orr * 8 + wv;
    const f32x4 w0 = *(const f32x4*)&Wq[d * 64 + part * 8];
    const f32x4 w1v = *(const f32x4*)&Wq[d * 64 + part * 8 + 4];
    float a = tm[0]*w0[0] + tm[1]*w0[1] + tm[2]*w0[2] + tm[3]*w0[3]
            + tm[4]*w1v[0] + tm[5]*w1v[1] + tm[6]*w1v[2] + tm[7]*w1v[3];
    a += __shfl_xor(a, 1); a += __shfl_xor(a, 2); a += __shfl_xor(a, 4);
    if (part == 0) qbuf[((size_t)b * 8 + sl) * 64 + d] = (bf16)(a * 0.125f);
  }
}

// ---------------- kA: logits + softmax + PV via MFMA ----------------
// grid 2048 = 128 b * 16 chunks of 128 tokens; block 256 (4 waves, 32 tok/wave)
__global__ __launch_bounds__(256) void kA(
    const bf16* __restrict__ kbuf, const bf16* __restrict__ vT,
    const bf16* __restrict__ qbuf,
    float* __restrict__ updpart, float* __restrict__ colpart)
{
  __shared__ bf16  qs[16][72];       // q rows 0..7, rows 8..15 zero
  __shared__ bf16  attn_b[16][136];  // [s][tok] bf16, rows 8..15 zero
  __shared__ float updp[4][8][64];
  __shared__ float cspart[4][8];

  const int bx  = blockIdx.x;
  const int b   = bx >> 4, ch = bx & 15;
  const int tid = threadIdx.x;
  const int lane = tid & 63, wvid = tid >> 6;
  const int l15 = lane & 15, quad = lane >> 4;
  const size_t tokbase = (size_t)b * 2048 + ch * 128;

  if (tid < 64) {
    const int s = tid >> 3, o = (tid & 7) * 8;
    *(bf16x8*)&qs[s][o] = *(const bf16x8*)&qbuf[((size_t)b * 8 + s) * 64 + o];
  } else if (tid < 128) {
    const int s = 8 + ((tid - 64) >> 3), o = ((tid - 64) & 7) * 8;
    uint32_t* zp = (uint32_t*)&qs[s][o];
    zp[0] = 0u; zp[1] = 0u; zp[2] = 0u; zp[3] = 0u;
  }
  {
    uint32_t* az = (uint32_t*)&attn_b[8][0];   // zero rows 8..15 (8*136 hw = 544 dw)
    for (int i = tid; i < 544; i += 256) az[i] = 0u;
  }
  __syncthreads();

  // logits (MFMA k @ q^T) + per-token softmax over s
  {
    float cs = 0.f;
    #pragma unroll
    for (int mt = 0; mt < 2; ++mt) {
      const int t0 = wvid * 32 + mt * 16;
      const bf16* kr = kbuf + (tokbase + t0 + l15) * 64 + quad * 8;
      f32x4 lg = {0.f, 0.f, 0.f, 0.f};
      lg = MFMA16(*(const bf16x8*)&kr[0],  *(const bf16x8*)&qs[l15][quad * 8],      lg);
      lg = MFMA16(*(const bf16x8*)&kr[32], *(const bf16x8*)&qs[l15][32 + quad * 8], lg);
      #pragma unroll
      for (int r = 0; r < 4; ++r) {
        const float l = lg[r];
        float m = l;
        m = fmaxf(m, __shfl_xor(m, 1));
        m = fmaxf(m, __shfl_xor(m, 2));
        m = fmaxf(m, __shfl_xor(m, 4));
        const float e = expf(l - m);
        float ss = e;
        ss += __shfl_xor(ss, 1);
        ss += __shfl_xor(ss, 2);
        ss += __shfl_xor(ss, 4);
        const float at = e / ss + 1e-8f;
        if (l15 < 8) {
          const bf16 ab = (bf16)at;
          attn_b[l15][t0 + quad * 4 + r] = ab;
          cs += (float)ab;
        }
      }
    }
    cs += __shfl_xor(cs, 16);
    cs += __shfl_xor(cs, 32);
    if (lane < 8) cspart[wvid][lane] = cs;
  }
  __syncthreads();

  // PV: per wave K=32 tokens; A = attn (A-frag-ready), B = vT rows from global
  {
    const bf16x8 afr = *(const bf16x8*)&attn_b[l15][wvid * 32 + quad * 8];
    const bf16* vrow = vT + (size_t)b * 131072 + (size_t)ch * 128 + wvid * 32 + quad * 8;
    const f32x4 zero4 = {0.f, 0.f, 0.f, 0.f};
    #pragma unroll
    for (int nt = 0; nt < 4; ++nt) {
      const bf16x8 bv = *(const bf16x8*)&vrow[(size_t)(nt * 16 + l15) * 2048];
      f32x4 dd = MFMA16(afr, bv, zero4);
      if (quad < 2) {
        #pragma unroll
        for (int r = 0; r < 4; ++r)
          updp[wvid][quad * 4 + r][nt * 16 + l15] = dd[r];
      }
    }
  }
  __syncthreads();

  {
    const float* up = &updp[0][0][0];
    float* og = updpart + ((size_t)b * 16 + ch) * 512;
    for (int o = tid; o < 512; o += 256)
      og[o] = up[o] + up[o + 512] + up[o + 1024] + up[o + 1536];
    if (tid < 8)
      colpart[((size_t)b * 16 + ch) * 8 + tid] =
        cspart[0][tid] + cspart[1][tid] + cspart[2][tid] + cspart[3][tid];
  }
}

// ---------------- kB: reduce + GRU + MLP + next-q / head ----------------
// grid 128, block 512. Broadcast-row scheme: 8 lanes per output, weight rows
// wave-uniform (no divergent global loads), shfl_xor(1,2,4) reduction.
__global__ __launch_bounds__(512) void kB(
    const float* __restrict__ updpart, const float* __restrict__ colpart,
    float* __restrict__ slotbuf, bf16* __restrict__ qbuf,
    const float* __restrict__ nsw, const float* __restrict__ nsb,
    const float* __restrict__ nmw, const float* __restrict__ nmb,
    const float* __restrict__ Wq,
    const float* __restrict__ wih, const float* __restrict__ whh,
    const float* __restrict__ bih, const float* __restrict__ bhh,
    const float* __restrict__ w1,  const float* __restrict__ b1,
    const float* __restrict__ w2,  const float* __restrict__ b2,
    const float* __restrict__ hwt, const float* __restrict__ hb,
    float* __restrict__ out, const int last)
{
  __shared__ float slots[8][66];
  __shared__ float tmp[8][66];
  __shared__ float gig[8][192], ghg[8][192];
  __shared__ float h1[8][132];
  const int b = blockIdx.x, tid = threadIdx.x;
  const int s0 = tid >> 6, d0 = tid & 63;      // wave == slot row
  const int part = tid & 7, sl = (tid >> 3) & 7, wv = tid >> 6;

  // updates reduce + slots load
  {
    const float* up = updpart + (size_t)b * 8192 + s0 * 64 + d0;
    float u = 0.f;
    #pragma unroll
    for (int ch = 0; ch < 16; ++ch) u += up[ch * 512];
    const float* cp = colpart + (size_t)b * 128 + s0;
    float cs = 0.f;
    #pragma unroll
    for (int ch = 0; ch < 16; ++ch) cs += cp[ch * 8];
    tmp[s0][d0] = u / cs;
    slots[s0][d0] = slotbuf[((size_t)b * 8 + s0) * 64 + d0];
  }
  __syncthreads();

  // GRU gates: wave wv computes j = jr*8+wv for all 8 slots
  {
    float tv[8], sv[8];
    #pragma unroll
    for (int i = 0; i < 8; ++i) { tv[i] = tmp[sl][part * 8 + i]; sv[i] = slots[sl][part * 8 + i]; }
    for (int jr = 0; jr < 24; ++jr) {
      const int j = jr * 8 + wv;
      const f32x4 wa0 = *(const f32x4*)&wih[j * 64 + part * 8];
      const f32x4 wa1 = *(const f32x4*)&wih[j * 64 + part * 8 + 4];
      const f32x4 wb0 = *(const f32x4*)&whh[j * 64 + part * 8];
      const f32x4 wb1 = *(const f32x4*)&whh[j * 64 + part * 8 + 4];
      float a = tv[0]*wa0[0] + tv[1]*wa0[1] + tv[2]*wa0[2] + tv[3]*wa0[3]
              + tv[4]*wa1[0] + tv[5]*wa1[1] + tv[6]*wa1[2] + tv[7]*wa1[3];
      float h = sv[0]*wb0[0] + sv[1]*wb0[1] + sv[2]*wb0[2] + sv[3]*wb0[3]
              + sv[4]*wb1[0] + sv[5]*wb1[1] + sv[6]*wb1[2] + sv[7]*wb1[3];
      a += __shfl_xor(a, 1); a += __shfl_xor(a, 2); a += __shfl_xor(a, 4);
      h += __shfl_xor(h, 1); h += __shfl_xor(h, 2); h += __shfl_xor(h, 4);
      if (part == 0) { gig[sl][j] = a + bih[j]; ghg[sl][j] = h + bhh[j]; }
    }
  }
  __syncthreads();

  float snew;
  {
    const float r  = 1.f / (1.f + expf(-(gig[s0][d0]       + ghg[s0][d0])));
    const float z  = 1.f / (1.f + expf(-(gig[s0][64 + d0]  + ghg[s0][64 + d0])));
    const float nn = tanhf(gig[s0][128 + d0] + r * ghg[s0][128 + d0]);
    snew = (1.f - z) * nn + z * slots[s0][d0];
    slots[s0][d0] = snew;
  }
  // LN(nm) via full-wave shuffle
  {
    float s = snew, s2 = snew * snew;
    #pragma unroll
    for (int m = 1; m < 64; m <<= 1) { s += __shfl_xor(s, m); s2 += __shfl_xor(s2, m); }
    const float mu = s * 0.015625f;
    const float rstd = rsqrtf(s2 * 0.015625f - mu * mu + 1e-5f);
    tmp[s0][d0] = (snew - mu) * rstd * nmw[d0] + nmb[d0];
  }
  __syncthreads();

  // MLP hidden
  {
    float tm[8];
    #pragma unroll
    for (int i = 0; i < 8; ++i) tm[i] = tmp[sl][part * 8 + i];
    for (int jr = 0; jr < 16; ++jr) {
      const int j = jr * 8 + wv;
      const f32x4 w0 = *(const f32x4*)&w1[j * 64 + part * 8];
      const f32x4 w1v = *(const f32x4*)&w1[j * 64 + part * 8 + 4];
      float a = tm[0]*w0[0] + tm[1]*w0[1] + tm[2]*w0[2] + tm[3]*w0[3]
              + tm[4]*w1v[0] + tm[5]*w1v[1] + tm[6]*w1v[2] + tm[7]*w1v[3];
      a += __shfl_xor(a, 1); a += __shfl_xor(a, 2); a += __shfl_xor(a, 4);
      if (part == 0) h1[sl][j] = fmaxf(a + b1[j], 0.f);
    }
  }
  __syncthreads();

  // MLP out + residual: wave wv computes d = orr*8+wv; 16 k per lane
  for (int orr = 0; orr < 8; ++orr) {
    const int d = orr * 8 + wv;
    float a = 0.f;
    #pragma unroll
    for (int i = 0; i < 4; ++i) {
      const f32x4 wv4 = *(const f32x4*)&w2[d * 128 + part * 16 + i * 4];
      a += h1[sl][part * 16 + i * 4 + 0] * wv4[0] + h1[sl][part * 16 + i * 4 + 1] * wv4[1]
         + h1[sl][part * 16 + i * 4 + 2] * wv4[2] + h1[sl][part * 16 + i * 4 + 3] * wv4[3];
    }
    a += __shfl_xor(a, 1); a += __shfl_xor(a, 2); a += __shfl_xor(a, 4);
    if (part == 0) slots[sl][d] += a + b2[d];
  }
  __syncthreads();

  const float sfin = slots[s0][d0];
  slotbuf[((size_t)b * 8 + s0) * 64 + d0] = sfin;

  if (!last) {
    float s = sfin, s2 = sfin * sfin;
    #pragma unroll
    for (int m = 1; m < 64; m <<= 1) { s += __shfl_xor(s, m); s2 += __shfl_xor(s2, m); }
    const float mu = s * 0.015625f;
    const float rstd = rsqrtf(s2 * 0.015625f - mu * mu + 1e-5f);
    tmp[s0][d0] = (sfin - mu) * rstd * nsw[d0] + nsb[d0];
    __syncthreads();
    float tm[8];
    #pragma unroll
    for (int i = 0; i < 8; ++i) tm[i] = tmp[sl][part * 8 + i];
    for (int orr = 0; orr < 8; ++orr) {
      const int d = orr * 8 + wv;
      const f32x4 w0 = *(const f32x4*)&Wq[d * 64 + part * 8];
      const f32x4 w1v = *(const f32x4*)&Wq[d * 64 + part * 8 + 4];
      float a = tm[0]*w0[0] + tm[1]*w0[1] + tm[2]*w0[2] + tm[3]*w0[3]
              + tm[4]*w1v[0] + tm[5]*w1v[1] + tm[6]*w1v[2] + tm[7]*w1v[3];
      a += __shfl_xor(a, 1); a += __shfl_xor(a, 2); a += __shfl_xor(a, 4);
      if (part == 0) qbuf[((size_t)b * 8 + sl) * 64 + d] = (bf16)(a * 0.125f);
    }
  } else {
    if (tid < 64) {
      float f = 0.f;
      #pragma unroll
      for (int s = 0; s < 8; ++s) f += slots[s][tid];
      tmp[0][tid] = f * 0.125f;
    }
    __syncthreads();
    if (tid < 15) {
      float a = hb[tid];
      for (int d = 0; d < 64; ++d) a += tmp[0][d] * hwt[tid * 64 + d];
      out[b * 15 + tid] = a;
    }
  }
}

extern "C" void kernel_launch(void* const* d_in, const int* in_sizes, int n_in,
                              void* d_out, int out_size, void* d_ws, size_t ws_size,
                              hipStream_t stream) {
  const float* x1   = (const float*)d_in[0];
  const float* x2   = (const float*)d_in[1];
  const float* c1w  = (const float*)d_in[2];
  const float* c1b  = (const float*)d_in[3];
  const float* c2w  = (const float*)d_in[4];
  const float* c2b  = (const float*)d_in[5];
  const float* nw   = (const float*)d_in[6];
  const float* nb   = (const float*)d_in[7];
  const float* niw  = (const float*)d_in[8];
  const float* nib  = (const float*)d_in[9];
  const float* nsw  = (const float*)d_in[10];
  const float* nsb  = (const float*)d_in[11];
  const float* nmw  = (const float*)d_in[12];
  const float* nmb  = (const float*)d_in[13];
  const float* smu  = (const float*)d_in[14];
  const float* slog = (const float*)d_in[15];
  const float* Wq   = (const float*)d_in[16];
  const float* Wk   = (const float*)d_in[17];
  const float* Wv   = (const float*)d_in[18];
  const float* wih  = (const float*)d_in[19];
  const float* whh  = (const float*)d_in[20];
  const float* bih  = (const float*)d_in[21];
  const float* bhh  = (const float*)d_in[22];
  const float* w1   = (const float*)d_in[23];
  const float* b1   = (const float*)d_in[24];
  const float* w2   = (const float*)d_in[25];
  const float* b2   = (const float*)d_in[26];
  const float* hwt  = (const float*)d_in[27];
  const float* hb   = (const float*)d_in[28];
  const float* noise= (const float*)d_in[29];

  char* ws = (char*)d_ws;
  bf16*  kbuf    = (bf16*)(ws);
  bf16*  vT      = (bf16*)(ws + (size_t)33554432);
  bf16*  wconv   = (bf16*)(ws + (size_t)67108864);
  bf16*  wkv     = (bf16*)(ws + (size_t)67174400);
  float* slotbuf = (float*)(ws + (size_t)67190784);
  bf16*  qbuf    = (bf16*)(ws + (size_t)67452928);
  float* updpart = (float*)(ws + (size_t)67584000);
  float* colpart = (float*)(ws + (size_t)71778304);

  k0_convert<<<dim3(64), dim3(256), 0, stream>>>(c1w, c2w, Wk, Wv, wconv, wkv);
  k1_conv_kv<<<dim3(4096), dim3(256), 0, stream>>>(x1, x2, c1b, c2b, nw, nb, niw, nib,
                                                   wconv, wkv, kbuf, vT);
  kS0<<<dim3(128), dim3(512), 0, stream>>>(smu, slog, noise, nsw, nsb, Wq, slotbuf, qbuf);
  for (int it = 0; it < 3; ++it) {
    kA<<<dim3(2048), dim3(256), 0, stream>>>(kbuf, vT, qbuf, updpart, colpart);
    kB<<<dim3(128), dim3(512), 0, stream>>>(updpart, colpart, slotbuf, qbuf,
                                            nsw, nsb, nmw, nmb, Wq,
                                            wih, whh, bih, bhh, w1, b1, w2, b2,
                                            hwt, hb, (float*)d_out, (it == 2) ? 1 : 0);
  }
}